// Round 4
// baseline (928.565 us; speedup 1.0000x reference)
//
#include <hip/hip_runtime.h>
#include <math.h>

typedef unsigned short u16;
typedef unsigned short u16x8 __attribute__((ext_vector_type(8)));
typedef _Float16 f16x8 __attribute__((ext_vector_type(8)));
typedef float f32x4 __attribute__((ext_vector_type(4)));

#define LOG2E 1.4426950408889634f

static __device__ __forceinline__ u16 f2h(float f) { return __builtin_bit_cast(u16, (_Float16)f); }
static __device__ __forceinline__ float h2f(u16 u) { return (float)__builtin_bit_cast(_Float16, u); }

// async global->LDS, 16B per lane; LDS dest = wave-uniform base + lane*16
static __device__ __forceinline__ void g2l16(const u16* g, u16* l) {
    __builtin_amdgcn_global_load_lds(
        (const __attribute__((address_space(1))) void*)g,
        (__attribute__((address_space(3))) void*)l, 16, 0, 0);
}

// load 8 fp32, convert to f16 bits
static __device__ __forceinline__ u16x8 ld8f(const float* p) {
    f32x4 a = *(const f32x4*)p;
    f32x4 b = *(const f32x4*)(p + 4);
    u16x8 r;
    r[0] = f2h(a[0]); r[1] = f2h(a[1]); r[2] = f2h(a[2]); r[3] = f2h(a[3]);
    r[4] = f2h(b[0]); r[5] = f2h(b[1]); r[6] = f2h(b[2]); r[7] = f2h(b[3]);
    return r;
}

// ---------------------------------------------------------------------------
// fp32 -> f16 convert (hidden_states), 8 elems/thread
// ---------------------------------------------------------------------------
__global__ __launch_bounds__(256) void cvt_hs(const float* __restrict__ s, u16* __restrict__ d) {
    const size_t e = ((size_t)blockIdx.x * 256 + threadIdx.x) * 8;
    *(u16x8*)(d + e) = ld8f(s + e);
}

// ---------------------------------------------------------------------------
// QKV GEMM: C = A[4096,2048] @ W[2048,2048]^T + b. A f16 via global_load_lds
// (unpadded LDS, XOR-swizzled -> conflict-free frag reads); W fp32 manual
// staged (pitch 40). z=0->Q, 1->K (normal [b*s][h*d]); z=2->V transposed
// [b,h,d,s] so attention PV reads V^T directly from global.
// ---------------------------------------------------------------------------
__global__ __launch_bounds__(256) void gemm_qkv(
    const u16* __restrict__ A,
    const float* __restrict__ Wq, const float* __restrict__ Wk, const float* __restrict__ Wv,
    const float* __restrict__ bq, const float* __restrict__ bk, const float* __restrict__ bv,
    u16* __restrict__ Cq, u16* __restrict__ Ck, u16* __restrict__ Cvt)
{
    constexpr int K = 2048, N = 2048;
    const int z = blockIdx.z;
    const float* W    = (z == 0) ? Wq : ((z == 1) ? Wk : Wv);
    const float* bias = (z == 0) ? bq : ((z == 1) ? bk : bv);
    const int m0 = blockIdx.y * 128, n0 = blockIdx.x * 128;

    __shared__ __attribute__((aligned(16))) u16 As[128 * 32];
    __shared__ __attribute__((aligned(16))) u16 Bs[128 * 40];

    const int tid = threadIdx.x, l = tid & 63, w = tid >> 6;
    const int quad = l >> 4, lan = l & 15;

    // A async staging: wave w, issue j covers rows w*32+j*16+(l>>2), colgrp swizzled
    const int sr = l >> 2, gcol = l & 3;
    const int gs0 = (gcol ^ ((w * 8 + (sr >> 2)) & 3)) * 8;
    const int gs1 = (gcol ^ ((w * 8 + 4 + (sr >> 2)) & 3)) * 8;
    const u16* pA0 = A + (size_t)(m0 + w * 32 + sr) * K + gs0;
    const u16* pA1 = A + (size_t)(m0 + w * 32 + 16 + sr) * K + gs1;
    u16* lA0 = &As[(w * 32) * 32];
    u16* lA1 = &As[(w * 32 + 16) * 32];

    // B manual staging (fp32 -> f16), pitch 40
    const int r0 = tid >> 2, k0c = (tid & 3) * 8;
    const int r1 = (tid + 256) >> 2, k1c = ((tid + 256) & 3) * 8;
    const float* pB0 = W + (size_t)(n0 + r0) * K + k0c;
    const float* pB1 = W + (size_t)(n0 + r1) * K + k1c;

    const int wm = (w >> 1) * 64, wn = (w & 1) * 64;
    const int swq = (quad ^ ((lan >> 2) & 3)) * 8;   // swizzled A-frag col group

    f32x4 acc[4][4] = {};

    for (int kt = 0; kt < K; kt += 32) {
        u16x8 b0 = ld8f(pB0 + kt);
        u16x8 b1 = ld8f(pB1 + kt);
        __syncthreads();                 // prev iter's LDS readers done
        g2l16(pA0 + kt, lA0);
        g2l16(pA1 + kt, lA1);
        *(u16x8*)(&Bs[r0 * 40 + k0c]) = b0;
        *(u16x8*)(&Bs[r1 * 40 + k1c]) = b1;
        __syncthreads();                 // drains vmcnt (DMA) + lgkm

        f16x8 af[4], bf[4];
#pragma unroll
        for (int i = 0; i < 4; i++)
            af[i] = __builtin_bit_cast(f16x8, *(const u16x8*)(&As[(wm + i * 16 + lan) * 32 + swq]));
#pragma unroll
        for (int j = 0; j < 4; j++)
            bf[j] = __builtin_bit_cast(f16x8, *(const u16x8*)(&Bs[(wn + j * 16 + lan) * 40 + quad * 8]));
#pragma unroll
        for (int i = 0; i < 4; i++)
#pragma unroll
            for (int j = 0; j < 4; j++)
                acc[i][j] = __builtin_amdgcn_mfma_f32_16x16x32_f16(af[i], bf[j], acc[i][j], 0, 0, 0);
    }

    // epilogue: C/D layout row=(lane>>4)*4+r, col=lane&15
    if (z < 2) {
        u16* C = (z == 0) ? Cq : Ck;
#pragma unroll
        for (int j = 0; j < 4; j++) {
            const int col = n0 + wn + j * 16 + lan;
            const float bj = bias[col];
#pragma unroll
            for (int i = 0; i < 4; i++)
#pragma unroll
                for (int r = 0; r < 4; r++) {
                    const int row = m0 + wm + i * 16 + quad * 4 + r;
                    C[(size_t)row * N + col] = f2h(acc[i][j][r] + bj);
                }
        }
    } else {
        // V transposed: row=(b,s), col=(h,d) -> Cvt[((b*16+h)*128+d)*2048 + s]
#pragma unroll
        for (int j = 0; j < 4; j++) {
            const int col = n0 + wn + j * 16 + lan;
            const int hh = col >> 7, dd = col & 127;
            const float bj = bias[col];
            u16* Cr = Cvt + ((size_t)(hh)*128 + dd) * 2048;
#pragma unroll
            for (int i = 0; i < 4; i++)
#pragma unroll
                for (int r = 0; r < 4; r++) {
                    const int row = m0 + wm + i * 16 + quad * 4 + r;
                    const int bb = row >> 11, ss = row & 2047;
                    Cr[(size_t)bb * 4194304 + ss] = f2h(acc[i][j][r] + bj);
                }
        }
    }
}

// ---------------------------------------------------------------------------
// RMSNorm (inner=2048) + RoPE + history key scale; in-place on f16 q/k.
// q pre-scaled by 1/sqrt(128).
// ---------------------------------------------------------------------------
__global__ __launch_bounds__(256) void norm_rope(
    u16* __restrict__ q, u16* __restrict__ k,
    const float* __restrict__ rot,
    const float* __restrict__ nqw, const float* __restrict__ nkw,
    const float* __restrict__ hks, const int* __restrict__ oclp)
{
    const int row = blockIdx.x;
    const int s = row & 2047;
    const int t = threadIdx.x;
    const size_t base = (size_t)row * 2048 + t * 8;

    u16x8 q8 = *(const u16x8*)(q + base);
    u16x8 k8 = *(const u16x8*)(k + base);

    float qf[8], kf[8];
    float sq = 0.f, sk = 0.f;
#pragma unroll
    for (int i = 0; i < 8; i++) {
        qf[i] = h2f(q8[i]); sq += qf[i] * qf[i];
        kf[i] = h2f(k8[i]); sk += kf[i] * kf[i];
    }
#pragma unroll
    for (int off = 32; off > 0; off >>= 1) {
        sq += __shfl_down(sq, off);
        sk += __shfl_down(sk, off);
    }
    __shared__ float rq[4], rk[4];
    const int wv = t >> 6;
    if ((t & 63) == 0) { rq[wv] = sq; rk[wv] = sk; }
    __syncthreads();
    const float tq = rq[0] + rq[1] + rq[2] + rq[3];
    const float tk = rk[0] + rk[1] + rk[2] + rk[3];
    const float scq = rsqrtf(tq * (1.0f / 2048.0f) + 1e-5f);
    const float sck = rsqrtf(tk * (1.0f / 2048.0f) + 1e-5f);
#pragma unroll
    for (int i = 0; i < 8; i++) {
        qf[i] *= scq * nqw[t * 8 + i];
        kf[i] *= sck * nkw[t * 8 + i];
    }
    const int e0 = t * 8;
    const int dh0 = e0 & 127;
    const int h = e0 >> 7;
    float qo[8], ko[8];
#pragma unroll
    for (int p = 0; p < 4; p++) {
        const int dh = dh0 + 2 * p;
        const float c  = rot[s * 256 + dh];
        const float sn = rot[s * 256 + 128 + dh + 1];
        qo[2 * p]     = qf[2 * p] * c  - qf[2 * p + 1] * sn;
        qo[2 * p + 1] = qf[2 * p] * sn + qf[2 * p + 1] * c;
        ko[2 * p]     = kf[2 * p] * c  - kf[2 * p + 1] * sn;
        ko[2 * p + 1] = kf[2 * p] * sn + kf[2 * p + 1] * c;
    }
    const float ATT = 0.08838834764831845f;
#pragma unroll
    for (int i = 0; i < 8; i++) qo[i] *= ATT;

    const int hist = 2048 - oclp[0];
    if (s < hist) {
        const float hv = hks[h];
        const float scl = 1.0f + 9.0f / (1.0f + expf(-hv));
#pragma unroll
        for (int i = 0; i < 8; i++) ko[i] *= scl;
    }

    u16x8 qo8, ko8;
#pragma unroll
    for (int i = 0; i < 8; i++) { qo8[i] = f2h(qo[i]); ko8[i] = f2h(ko[i]); }
    *(u16x8*)(q + base) = qo8;
    *(u16x8*)(k + base) = ko8;
}

// ---------------------------------------------------------------------------
// Flash attention v2: NO barriers, NO K/V LDS staging. K read natural
// [b,s,h,d] (d-contig = B-operand ready); V read from pre-transposed
// [b,h,d,s]. Only P goes through per-wave LDS. 8 waves x 16 q-rows.
// ---------------------------------------------------------------------------
__global__ __launch_bounds__(512, 4) void flash_attn2(
    const u16* __restrict__ Q, const u16* __restrict__ Kr, const u16* __restrict__ Vt,
    u16* __restrict__ O)
{
    const int qt = blockIdx.x;        // 0..15
    const int bh = blockIdx.y;        // 0..31
    const int b = bh >> 4, h = bh & 15;
    const int tid = threadIdx.x, l = tid & 63, w = tid >> 6;
    const int quad = l >> 4, lan = l & 15;

    __shared__ __attribute__((aligned(16))) u16 Pb[8][16 * 72];

    f16x8 qf[4];
    {
        const u16* qp = Q + ((size_t)(b * 2048 + qt * 128 + w * 16 + lan)) * 2048 + h * 128 + quad * 8;
#pragma unroll
        for (int ks = 0; ks < 4; ks++)
            qf[ks] = __builtin_bit_cast(f16x8, *(const u16x8*)(qp + ks * 32));
    }

    const u16* kp = Kr + ((size_t)(b * 2048 + lan)) * 2048 + h * 128 + quad * 8;
    const u16* vp = Vt + ((size_t)((b * 16 + h) * 128 + lan)) * 2048 + quad * 8;

    float mr[4], lrp[4];
    f32x4 o[8] = {};
#pragma unroll
    for (int r = 0; r < 4; r++) { mr[r] = -3.0e38f; lrp[r] = 0.f; }

    for (int kt = 0; kt < 32; kt++) {
        // S = Q K^T : B-frags straight from global (L1/L2)
        f32x4 sfr[4] = {};
        const u16* kpt = kp + (size_t)kt * 64 * 2048;
#pragma unroll
        for (int ks = 0; ks < 4; ks++) {
            f16x8 kb[4];
#pragma unroll
            for (int nt = 0; nt < 4; nt++)
                kb[nt] = __builtin_bit_cast(f16x8,
                    *(const u16x8*)(kpt + (size_t)nt * 16 * 2048 + ks * 32));
#pragma unroll
            for (int nt = 0; nt < 4; nt++)
                sfr[nt] = __builtin_amdgcn_mfma_f32_16x16x32_f16(qf[ks], kb[nt], sfr[nt], 0, 0, 0);
        }

        // online softmax: max across 16 lanes of quad; sum kept per-lane (deferred)
        float tm[4];
#pragma unroll
        for (int r = 0; r < 4; r++)
            tm[r] = fmaxf(fmaxf(sfr[0][r], sfr[1][r]), fmaxf(sfr[2][r], sfr[3][r]));
#pragma unroll
        for (int mask = 1; mask <= 8; mask <<= 1)
#pragma unroll
            for (int r = 0; r < 4; r++) tm[r] = fmaxf(tm[r], __shfl_xor(tm[r], mask));

        float al[4];
#pragma unroll
        for (int r = 0; r < 4; r++) {
            const float mn = fmaxf(mr[r], tm[r]);
            al[r] = exp2f((mr[r] - mn) * LOG2E);
            mr[r] = mn;
        }
        float ps[4] = {0.f, 0.f, 0.f, 0.f};
#pragma unroll
        for (int nt = 0; nt < 4; nt++)
#pragma unroll
            for (int r = 0; r < 4; r++) {
                const float p = exp2f((sfr[nt][r] - mr[r]) * LOG2E);
                ps[r] += p;
                Pb[w][(quad * 4 + r) * 72 + nt * 16 + lan] = f2h(p);
            }
#pragma unroll
        for (int r = 0; r < 4; r++) lrp[r] = lrp[r] * al[r] + ps[r];
#pragma unroll
        for (int nd = 0; nd < 8; nd++)
#pragma unroll
            for (int r = 0; r < 4; r++) o[nd][r] *= al[r];

        __asm__ volatile("s_waitcnt lgkmcnt(0)" ::: "memory");

        // O += P @ V : V^T-frags straight from global
        const u16* vpt = vp + kt * 64;
#pragma unroll
        for (int ks2 = 0; ks2 < 2; ks2++) {
            f16x8 pf = __builtin_bit_cast(f16x8,
                *(const u16x8*)(&Pb[w][lan * 72 + ks2 * 32 + quad * 8]));
#pragma unroll
            for (int nd = 0; nd < 8; nd++) {
                f16x8 vtf = __builtin_bit_cast(f16x8,
                    *(const u16x8*)(vpt + (size_t)nd * 16 * 2048 + ks2 * 32));
                o[nd] = __builtin_amdgcn_mfma_f32_16x16x32_f16(pf, vtf, o[nd], 0, 0, 0);
            }
        }
    }

    // finalize: reduce deferred sums across the quad's 16 lanes
#pragma unroll
    for (int mask = 1; mask <= 8; mask <<= 1)
#pragma unroll
        for (int r = 0; r < 4; r++) lrp[r] += __shfl_xor(lrp[r], mask);

#pragma unroll
    for (int nd = 0; nd < 8; nd++)
#pragma unroll
        for (int r = 0; r < 4; r++) {
            const int srow = qt * 128 + w * 16 + quad * 4 + r;
            O[((size_t)(b * 2048 + srow)) * 2048 + h * 128 + nd * 16 + lan] = f2h(o[nd][r] / lrp[r]);
        }
}

// ---------------------------------------------------------------------------
// Output projection: A = aout (f16, async), W = Wo (fp32, manual), C fp32.
// ---------------------------------------------------------------------------
__global__ __launch_bounds__(256) void gemm_out(
    const u16* __restrict__ A, const float* __restrict__ W,
    const float* __restrict__ bias, float* __restrict__ C)
{
    constexpr int K = 2048, N = 2048;
    const int m0 = blockIdx.y * 128, n0 = blockIdx.x * 128;

    __shared__ __attribute__((aligned(16))) u16 As[128 * 32];
    __shared__ __attribute__((aligned(16))) u16 Bs[128 * 40];

    const int tid = threadIdx.x, l = tid & 63, w = tid >> 6;
    const int quad = l >> 4, lan = l & 15;

    const int sr = l >> 2, gcol = l & 3;
    const int gs0 = (gcol ^ ((w * 8 + (sr >> 2)) & 3)) * 8;
    const int gs1 = (gcol ^ ((w * 8 + 4 + (sr >> 2)) & 3)) * 8;
    const u16* pA0 = A + (size_t)(m0 + w * 32 + sr) * K + gs0;
    const u16* pA1 = A + (size_t)(m0 + w * 32 + 16 + sr) * K + gs1;
    u16* lA0 = &As[(w * 32) * 32];
    u16* lA1 = &As[(w * 32 + 16) * 32];

    const int r0 = tid >> 2, k0c = (tid & 3) * 8;
    const int r1 = (tid + 256) >> 2, k1c = ((tid + 256) & 3) * 8;
    const float* pB0 = W + (size_t)(n0 + r0) * K + k0c;
    const float* pB1 = W + (size_t)(n0 + r1) * K + k1c;

    const int wm = (w >> 1) * 64, wn = (w & 1) * 64;
    const int swq = (quad ^ ((lan >> 2) & 3)) * 8;

    f32x4 acc[4][4] = {};

    for (int kt = 0; kt < K; kt += 32) {
        u16x8 b0 = ld8f(pB0 + kt);
        u16x8 b1 = ld8f(pB1 + kt);
        __syncthreads();
        g2l16(pA0 + kt, lA0);
        g2l16(pA1 + kt, lA1);
        *(u16x8*)(&Bs[r0 * 40 + k0c]) = b0;
        *(u16x8*)(&Bs[r1 * 40 + k1c]) = b1;
        __syncthreads();

        f16x8 af[4], bf[4];
#pragma unroll
        for (int i = 0; i < 4; i++)
            af[i] = __builtin_bit_cast(f16x8, *(const u16x8*)(&As[(wm + i * 16 + lan) * 32 + swq]));
#pragma unroll
        for (int j = 0; j < 4; j++)
            bf[j] = __builtin_bit_cast(f16x8, *(const u16x8*)(&Bs[(wn + j * 16 + lan) * 40 + quad * 8]));
#pragma unroll
        for (int i = 0; i < 4; i++)
#pragma unroll
            for (int j = 0; j < 4; j++)
                acc[i][j] = __builtin_amdgcn_mfma_f32_16x16x32_f16(af[i], bf[j], acc[i][j], 0, 0, 0);
    }

#pragma unroll
    for (int j = 0; j < 4; j++) {
        const int col = n0 + wn + j * 16 + lan;
        const float bj = bias[col];
#pragma unroll
        for (int i = 0; i < 4; i++)
#pragma unroll
            for (int r = 0; r < 4; r++) {
                const int row = m0 + wm + i * 16 + quad * 4 + r;
                C[(size_t)row * N + col] = acc[i][j][r] + bj;
            }
    }
}

// ---------------------------------------------------------------------------
extern "C" void kernel_launch(void* const* d_in, const int* in_sizes, int n_in,
                              void* d_out, int out_size, void* d_ws, size_t ws_size,
                              hipStream_t stream) {
    const float* hs  = (const float*)d_in[0];
    const float* rot = (const float*)d_in[1];
    const float* Wq  = (const float*)d_in[2];
    const float* bq  = (const float*)d_in[3];
    const float* Wk  = (const float*)d_in[4];
    const float* bk  = (const float*)d_in[5];
    const float* Wv  = (const float*)d_in[6];
    const float* bv  = (const float*)d_in[7];
    const float* nqw = (const float*)d_in[8];
    const float* nkw = (const float*)d_in[9];
    const float* hks = (const float*)d_in[10];
    const float* Wo  = (const float*)d_in[11];
    const float* bo  = (const float*)d_in[12];
    const int*   ocl = (const int*)d_in[13];

    // ws (64 MiB): qraw | kraw | vtr | aout, 16 MiB each
    u16* qraw = (u16*)d_ws;
    u16* kraw = qraw + 8388608;
    u16* vtr  = kraw + 8388608;
    u16* aout = vtr + 8388608;
    float* out = (float*)d_out;
    // hs16 scratch in d_out's first 16 MiB (dead before gemm_out writes C)
    u16* hs16 = (u16*)d_out;

    // 0) hs fp32 -> f16
    cvt_hs<<<dim3(4096), 256, 0, stream>>>(hs, hs16);
    // 1) QKV projection; z=2 writes V transposed [b,h,d,s]
    gemm_qkv<<<dim3(16, 32, 3), 256, 0, stream>>>(
        hs16, Wq, Wk, Wv, bq, bk, bv, qraw, kraw, vtr);
    // 2) rmsnorm + rope + history scale (in place, f16)
    norm_rope<<<dim3(4096), 256, 0, stream>>>(qraw, kraw, rot, nqw, nkw, hks, ocl);
    // 3) flash attention (barrier-free) -> aout
    flash_attn2<<<dim3(16, 32), 512, 0, stream>>>(qraw, kraw, vtr, aout);
    // 4) output projection -> d_out (fp32)
    gemm_out<<<dim3(16, 32), 256, 0, stream>>>(aout, Wo, bo, out);
}

// Round 5
// 610.770 us; speedup vs baseline: 1.5203x; 1.5203x over previous
//
#include <hip/hip_runtime.h>
#include <math.h>

typedef unsigned short u16;
typedef unsigned short u16x8 __attribute__((ext_vector_type(8)));
typedef _Float16 f16x8 __attribute__((ext_vector_type(8)));
typedef float f32x4 __attribute__((ext_vector_type(4)));

#define LOG2E 1.4426950408889634f

static __device__ __forceinline__ u16 f2h(float f) { return __builtin_bit_cast(u16, (_Float16)f); }
static __device__ __forceinline__ float h2f(u16 u) { return (float)__builtin_bit_cast(_Float16, u); }

// async global->LDS, 16B per lane; LDS dest = wave-uniform base + lane*16
static __device__ __forceinline__ void g2l16(const u16* g, u16* l) {
    __builtin_amdgcn_global_load_lds(
        (const __attribute__((address_space(1))) void*)g,
        (__attribute__((address_space(3))) void*)l, 16, 0, 0);
}

// load 8 fp32, convert to f16 bits
static __device__ __forceinline__ u16x8 ld8f(const float* p) {
    f32x4 a = *(const f32x4*)p;
    f32x4 b = *(const f32x4*)(p + 4);
    u16x8 r;
    r[0] = f2h(a[0]); r[1] = f2h(a[1]); r[2] = f2h(a[2]); r[3] = f2h(a[3]);
    r[4] = f2h(b[0]); r[5] = f2h(b[1]); r[6] = f2h(b[2]); r[7] = f2h(b[3]);
    return r;
}

// ---------------------------------------------------------------------------
// fp32 -> f16 convert (hidden_states), 8 elems/thread
// ---------------------------------------------------------------------------
__global__ __launch_bounds__(256) void cvt_hs(const float* __restrict__ s, u16* __restrict__ d) {
    const size_t e = ((size_t)blockIdx.x * 256 + threadIdx.x) * 8;
    *(u16x8*)(d + e) = ld8f(s + e);
}

// ---------------------------------------------------------------------------
// QKV GEMM: C = A[4096,2048] @ W[2048,2048]^T + b. A f16 via global_load_lds
// (unpadded LDS, XOR-swizzled); W fp32 manual staged (pitch 40).
// z=0->Q, 1->K (normal [b*s][h*d]); z=2->V transposed [b,h,d,s].
// ---------------------------------------------------------------------------
__global__ __launch_bounds__(256) void gemm_qkv(
    const u16* __restrict__ A,
    const float* __restrict__ Wq, const float* __restrict__ Wk, const float* __restrict__ Wv,
    const float* __restrict__ bq, const float* __restrict__ bk, const float* __restrict__ bv,
    u16* __restrict__ Cq, u16* __restrict__ Ck, u16* __restrict__ Cvt)
{
    constexpr int K = 2048, N = 2048;
    const int z = blockIdx.z;
    const float* W    = (z == 0) ? Wq : ((z == 1) ? Wk : Wv);
    const float* bias = (z == 0) ? bq : ((z == 1) ? bk : bv);
    const int m0 = blockIdx.y * 128, n0 = blockIdx.x * 128;

    __shared__ __attribute__((aligned(16))) u16 As[128 * 32];
    __shared__ __attribute__((aligned(16))) u16 Bs[128 * 40];

    const int tid = threadIdx.x, l = tid & 63, w = tid >> 6;
    const int quad = l >> 4, lan = l & 15;

    const int sr = l >> 2, gcol = l & 3;
    const int gs0 = (gcol ^ ((w * 8 + (sr >> 2)) & 3)) * 8;
    const int gs1 = (gcol ^ ((w * 8 + 4 + (sr >> 2)) & 3)) * 8;
    const u16* pA0 = A + (size_t)(m0 + w * 32 + sr) * K + gs0;
    const u16* pA1 = A + (size_t)(m0 + w * 32 + 16 + sr) * K + gs1;
    u16* lA0 = &As[(w * 32) * 32];
    u16* lA1 = &As[(w * 32 + 16) * 32];

    const int r0 = tid >> 2, k0c = (tid & 3) * 8;
    const int r1 = (tid + 256) >> 2, k1c = ((tid + 256) & 3) * 8;
    const float* pB0 = W + (size_t)(n0 + r0) * K + k0c;
    const float* pB1 = W + (size_t)(n0 + r1) * K + k1c;

    const int wm = (w >> 1) * 64, wn = (w & 1) * 64;
    const int swq = (quad ^ ((lan >> 2) & 3)) * 8;

    f32x4 acc[4][4] = {};

    for (int kt = 0; kt < K; kt += 32) {
        u16x8 b0 = ld8f(pB0 + kt);
        u16x8 b1 = ld8f(pB1 + kt);
        __syncthreads();
        g2l16(pA0 + kt, lA0);
        g2l16(pA1 + kt, lA1);
        *(u16x8*)(&Bs[r0 * 40 + k0c]) = b0;
        *(u16x8*)(&Bs[r1 * 40 + k1c]) = b1;
        __syncthreads();

        f16x8 af[4], bf[4];
#pragma unroll
        for (int i = 0; i < 4; i++)
            af[i] = __builtin_bit_cast(f16x8, *(const u16x8*)(&As[(wm + i * 16 + lan) * 32 + swq]));
#pragma unroll
        for (int j = 0; j < 4; j++)
            bf[j] = __builtin_bit_cast(f16x8, *(const u16x8*)(&Bs[(wn + j * 16 + lan) * 40 + quad * 8]));
#pragma unroll
        for (int i = 0; i < 4; i++)
#pragma unroll
            for (int j = 0; j < 4; j++)
                acc[i][j] = __builtin_amdgcn_mfma_f32_16x16x32_f16(af[i], bf[j], acc[i][j], 0, 0, 0);
    }

    if (z < 2) {
        u16* C = (z == 0) ? Cq : Ck;
#pragma unroll
        for (int j = 0; j < 4; j++) {
            const int col = n0 + wn + j * 16 + lan;
            const float bj = bias[col];
#pragma unroll
            for (int i = 0; i < 4; i++)
#pragma unroll
                for (int r = 0; r < 4; r++) {
                    const int row = m0 + wm + i * 16 + quad * 4 + r;
                    C[(size_t)row * N + col] = f2h(acc[i][j][r] + bj);
                }
        }
    } else {
        // V transposed: row=(b,s), col=(h,d) -> Cvt[((b*16+h)*128+d)*2048 + s]
#pragma unroll
        for (int j = 0; j < 4; j++) {
            const int col = n0 + wn + j * 16 + lan;
            const int hh = col >> 7, dd = col & 127;
            const float bj = bias[col];
            u16* Cr = Cvt + ((size_t)(hh)*128 + dd) * 2048;
#pragma unroll
            for (int i = 0; i < 4; i++)
#pragma unroll
                for (int r = 0; r < 4; r++) {
                    const int row = m0 + wm + i * 16 + quad * 4 + r;
                    const int bb = row >> 11, ss = row & 2047;
                    Cr[(size_t)bb * 4194304 + ss] = f2h(acc[i][j][r] + bj);
                }
        }
    }
}

// ---------------------------------------------------------------------------
// RMSNorm (inner=2048) + RoPE + history key scale; in-place on f16 q/k.
// q pre-scaled by 1/sqrt(128).
// ---------------------------------------------------------------------------
__global__ __launch_bounds__(256) void norm_rope(
    u16* __restrict__ q, u16* __restrict__ k,
    const float* __restrict__ rot,
    const float* __restrict__ nqw, const float* __restrict__ nkw,
    const float* __restrict__ hks, const int* __restrict__ oclp)
{
    const int row = blockIdx.x;
    const int s = row & 2047;
    const int t = threadIdx.x;
    const size_t base = (size_t)row * 2048 + t * 8;

    u16x8 q8 = *(const u16x8*)(q + base);
    u16x8 k8 = *(const u16x8*)(k + base);

    float qf[8], kf[8];
    float sq = 0.f, sk = 0.f;
#pragma unroll
    for (int i = 0; i < 8; i++) {
        qf[i] = h2f(q8[i]); sq += qf[i] * qf[i];
        kf[i] = h2f(k8[i]); sk += kf[i] * kf[i];
    }
#pragma unroll
    for (int off = 32; off > 0; off >>= 1) {
        sq += __shfl_down(sq, off);
        sk += __shfl_down(sk, off);
    }
    __shared__ float rq[4], rk[4];
    const int wv = t >> 6;
    if ((t & 63) == 0) { rq[wv] = sq; rk[wv] = sk; }
    __syncthreads();
    const float tq = rq[0] + rq[1] + rq[2] + rq[3];
    const float tk = rk[0] + rk[1] + rk[2] + rk[3];
    const float scq = rsqrtf(tq * (1.0f / 2048.0f) + 1e-5f);
    const float sck = rsqrtf(tk * (1.0f / 2048.0f) + 1e-5f);
#pragma unroll
    for (int i = 0; i < 8; i++) {
        qf[i] *= scq * nqw[t * 8 + i];
        kf[i] *= sck * nkw[t * 8 + i];
    }
    const int e0 = t * 8;
    const int dh0 = e0 & 127;
    const int h = e0 >> 7;
    float qo[8], ko[8];
#pragma unroll
    for (int p = 0; p < 4; p++) {
        const int dh = dh0 + 2 * p;
        const float c  = rot[s * 256 + dh];
        const float sn = rot[s * 256 + 128 + dh + 1];
        qo[2 * p]     = qf[2 * p] * c  - qf[2 * p + 1] * sn;
        qo[2 * p + 1] = qf[2 * p] * sn + qf[2 * p + 1] * c;
        ko[2 * p]     = kf[2 * p] * c  - kf[2 * p + 1] * sn;
        ko[2 * p + 1] = kf[2 * p] * sn + kf[2 * p + 1] * c;
    }
    const float ATT = 0.08838834764831845f;
#pragma unroll
    for (int i = 0; i < 8; i++) qo[i] *= ATT;

    const int hist = 2048 - oclp[0];
    if (s < hist) {
        const float hv = hks[h];
        const float scl = 1.0f + 9.0f / (1.0f + expf(-hv));
#pragma unroll
        for (int i = 0; i < 8; i++) ko[i] *= scl;
    }

    u16x8 qo8, ko8;
#pragma unroll
    for (int i = 0; i < 8; i++) { qo8[i] = f2h(qo[i]); ko8[i] = f2h(ko[i]); }
    *(u16x8*)(q + base) = qo8;
    *(u16x8*)(k + base) = ko8;
}

// ---------------------------------------------------------------------------
// Flash attention v3: LDS-staged K and pre-transposed V (coalesced b128
// copies, no in-kernel transpose), software-pipelined: next tile's global
// loads issue before current tile's MFMA block. 8 waves x 16 q-rows,
// K-tile 64. LDS = 17408 + 18432 + 18432 = 54272 B -> 2 blocks/CU.
// ---------------------------------------------------------------------------
__global__ __launch_bounds__(512) void flash_attn3(
    const u16* __restrict__ Q, const u16* __restrict__ Kr, const u16* __restrict__ Vt,
    u16* __restrict__ O)
{
    const int qt = blockIdx.x;        // 0..15
    const int bh = blockIdx.y;        // 0..31
    const int b = bh >> 4, h = bh & 15;
    const int tid = threadIdx.x, l = tid & 63, w = tid >> 6;
    const int quad = l >> 4, lan = l & 15;

    __shared__ __attribute__((aligned(16))) u16 Kb[64 * 136];
    __shared__ __attribute__((aligned(16))) u16 VTb[128 * 72];
    __shared__ __attribute__((aligned(16))) u16 Pb[8][16 * 72];

    // Q A-frags (q pre-scaled by 1/sqrt(128))
    f16x8 qf[4];
    {
        const u16* qp = Q + ((size_t)(b * 2048 + qt * 128 + w * 16 + lan)) * 2048 + h * 128 + quad * 8;
#pragma unroll
        for (int ks = 0; ks < 4; ks++)
            qf[ks] = __builtin_bit_cast(f16x8, *(const u16x8*)(qp + ks * 32));
    }

    // staging addresses: 1024 chunks of 8 per tile, 2 chunks/thread
    const int c0 = tid, c1 = tid + 512;
    const int kp0 = c0 >> 4, kd0 = (c0 & 15) * 8;   // K: [kpos][d]
    const int kp1 = c1 >> 4, kd1 = (c1 & 15) * 8;
    const int vd0 = c0 >> 3, vs0 = (c0 & 7) * 8;    // VT: [d][s]
    const int vd1 = c1 >> 3, vs1 = (c1 & 7) * 8;
    const u16* kbase = Kr + ((size_t)(b * 2048)) * 2048 + h * 128;
    const u16* vbase = Vt + ((size_t)((b * 16 + h) * 128)) * 2048;

    float mr[4], lrp[4];
    f32x4 o[8] = {};
#pragma unroll
    for (int r = 0; r < 4; r++) { mr[r] = -3.0e38f; lrp[r] = 0.f; }

    // prefetch tile 0
    u16x8 kv0 = *(const u16x8*)(kbase + (size_t)(0 + kp0) * 2048 + kd0);
    u16x8 kv1 = *(const u16x8*)(kbase + (size_t)(0 + kp1) * 2048 + kd1);
    u16x8 vv0 = *(const u16x8*)(vbase + (size_t)vd0 * 2048 + 0 + vs0);
    u16x8 vv1 = *(const u16x8*)(vbase + (size_t)vd1 * 2048 + 0 + vs1);

    for (int kt = 0; kt < 32; kt++) {
        __syncthreads();               // prior tile's LDS readers done
        *(u16x8*)(&Kb[kp0 * 136 + kd0]) = kv0;
        *(u16x8*)(&Kb[kp1 * 136 + kd1]) = kv1;
        *(u16x8*)(&VTb[vd0 * 72 + vs0]) = vv0;
        *(u16x8*)(&VTb[vd1 * 72 + vs1]) = vv1;
        __syncthreads();

        // prefetch next tile (overlaps with this tile's MFMA)
        if (kt < 31) {
            const int kn = (kt + 1) * 64;
            kv0 = *(const u16x8*)(kbase + (size_t)(kn + kp0) * 2048 + kd0);
            kv1 = *(const u16x8*)(kbase + (size_t)(kn + kp1) * 2048 + kd1);
            vv0 = *(const u16x8*)(vbase + (size_t)vd0 * 2048 + kn + vs0);
            vv1 = *(const u16x8*)(vbase + (size_t)vd1 * 2048 + kn + vs1);
        }

        // S = Q K^T  (16 x 64 per wave)
        f32x4 sfr[4] = {};
#pragma unroll
        for (int ks = 0; ks < 4; ks++)
#pragma unroll
            for (int nt = 0; nt < 4; nt++) {
                f16x8 kb = __builtin_bit_cast(f16x8,
                    *(const u16x8*)(&Kb[(nt * 16 + lan) * 136 + ks * 32 + quad * 8]));
                sfr[nt] = __builtin_amdgcn_mfma_f32_16x16x32_f16(qf[ks], kb, sfr[nt], 0, 0, 0);
            }

        // online softmax: quad-wide max; per-lane deferred sum
        float tm[4];
#pragma unroll
        for (int r = 0; r < 4; r++)
            tm[r] = fmaxf(fmaxf(sfr[0][r], sfr[1][r]), fmaxf(sfr[2][r], sfr[3][r]));
#pragma unroll
        for (int mask = 1; mask <= 8; mask <<= 1)
#pragma unroll
            for (int r = 0; r < 4; r++) tm[r] = fmaxf(tm[r], __shfl_xor(tm[r], mask));

        float al[4];
#pragma unroll
        for (int r = 0; r < 4; r++) {
            const float mn = fmaxf(mr[r], tm[r]);
            al[r] = exp2f((mr[r] - mn) * LOG2E);
            mr[r] = mn;
        }
        float ps[4] = {0.f, 0.f, 0.f, 0.f};
#pragma unroll
        for (int nt = 0; nt < 4; nt++)
#pragma unroll
            for (int r = 0; r < 4; r++) {
                const float p = exp2f((sfr[nt][r] - mr[r]) * LOG2E);
                ps[r] += p;
                Pb[w][(quad * 4 + r) * 72 + nt * 16 + lan] = f2h(p);
            }
#pragma unroll
        for (int r = 0; r < 4; r++) lrp[r] = lrp[r] * al[r] + ps[r];
#pragma unroll
        for (int nd = 0; nd < 8; nd++)
#pragma unroll
            for (int r = 0; r < 4; r++) o[nd][r] *= al[r];

        __asm__ volatile("s_waitcnt lgkmcnt(0)" ::: "memory");  // own-wave P visible

        // O += P @ V
#pragma unroll
        for (int ks2 = 0; ks2 < 2; ks2++) {
            f16x8 pf = __builtin_bit_cast(f16x8,
                *(const u16x8*)(&Pb[w][lan * 72 + ks2 * 32 + quad * 8]));
#pragma unroll
            for (int nd = 0; nd < 8; nd++) {
                f16x8 vtf = __builtin_bit_cast(f16x8,
                    *(const u16x8*)(&VTb[(nd * 16 + lan) * 72 + ks2 * 32 + quad * 8]));
                o[nd] = __builtin_amdgcn_mfma_f32_16x16x32_f16(pf, vtf, o[nd], 0, 0, 0);
            }
        }
    }

    // finalize deferred sums across the quad's 16 lanes
#pragma unroll
    for (int mask = 1; mask <= 8; mask <<= 1)
#pragma unroll
        for (int r = 0; r < 4; r++) lrp[r] += __shfl_xor(lrp[r], mask);

#pragma unroll
    for (int nd = 0; nd < 8; nd++)
#pragma unroll
        for (int r = 0; r < 4; r++) {
            const int srow = qt * 128 + w * 16 + quad * 4 + r;
            O[((size_t)(b * 2048 + srow)) * 2048 + h * 128 + nd * 16 + lan] = f2h(o[nd][r] / lrp[r]);
        }
}

// ---------------------------------------------------------------------------
// Output projection: A = aout (f16, async), W = Wo (fp32, manual), C fp32.
// ---------------------------------------------------------------------------
__global__ __launch_bounds__(256) void gemm_out(
    const u16* __restrict__ A, const float* __restrict__ W,
    const float* __restrict__ bias, float* __restrict__ C)
{
    constexpr int K = 2048, N = 2048;
    const int m0 = blockIdx.y * 128, n0 = blockIdx.x * 128;

    __shared__ __attribute__((aligned(16))) u16 As[128 * 32];
    __shared__ __attribute__((aligned(16))) u16 Bs[128 * 40];

    const int tid = threadIdx.x, l = tid & 63, w = tid >> 6;
    const int quad = l >> 4, lan = l & 15;

    const int sr = l >> 2, gcol = l & 3;
    const int gs0 = (gcol ^ ((w * 8 + (sr >> 2)) & 3)) * 8;
    const int gs1 = (gcol ^ ((w * 8 + 4 + (sr >> 2)) & 3)) * 8;
    const u16* pA0 = A + (size_t)(m0 + w * 32 + sr) * K + gs0;
    const u16* pA1 = A + (size_t)(m0 + w * 32 + 16 + sr) * K + gs1;
    u16* lA0 = &As[(w * 32) * 32];
    u16* lA1 = &As[(w * 32 + 16) * 32];

    const int r0 = tid >> 2, k0c = (tid & 3) * 8;
    const int r1 = (tid + 256) >> 2, k1c = ((tid + 256) & 3) * 8;
    const float* pB0 = W + (size_t)(n0 + r0) * K + k0c;
    const float* pB1 = W + (size_t)(n0 + r1) * K + k1c;

    const int wm = (w >> 1) * 64, wn = (w & 1) * 64;
    const int swq = (quad ^ ((lan >> 2) & 3)) * 8;

    f32x4 acc[4][4] = {};

    for (int kt = 0; kt < K; kt += 32) {
        u16x8 b0 = ld8f(pB0 + kt);
        u16x8 b1 = ld8f(pB1 + kt);
        __syncthreads();
        g2l16(pA0 + kt, lA0);
        g2l16(pA1 + kt, lA1);
        *(u16x8*)(&Bs[r0 * 40 + k0c]) = b0;
        *(u16x8*)(&Bs[r1 * 40 + k1c]) = b1;
        __syncthreads();

        f16x8 af[4], bf[4];
#pragma unroll
        for (int i = 0; i < 4; i++)
            af[i] = __builtin_bit_cast(f16x8, *(const u16x8*)(&As[(wm + i * 16 + lan) * 32 + swq]));
#pragma unroll
        for (int j = 0; j < 4; j++)
            bf[j] = __builtin_bit_cast(f16x8, *(const u16x8*)(&Bs[(wn + j * 16 + lan) * 40 + quad * 8]));
#pragma unroll
        for (int i = 0; i < 4; i++)
#pragma unroll
            for (int j = 0; j < 4; j++)
                acc[i][j] = __builtin_amdgcn_mfma_f32_16x16x32_f16(af[i], bf[j], acc[i][j], 0, 0, 0);
    }

#pragma unroll
    for (int j = 0; j < 4; j++) {
        const int col = n0 + wn + j * 16 + lan;
        const float bj = bias[col];
#pragma unroll
        for (int i = 0; i < 4; i++)
#pragma unroll
            for (int r = 0; r < 4; r++) {
                const int row = m0 + wm + i * 16 + quad * 4 + r;
                C[(size_t)row * N + col] = acc[i][j][r] + bj;
            }
    }
}

// ---------------------------------------------------------------------------
extern "C" void kernel_launch(void* const* d_in, const int* in_sizes, int n_in,
                              void* d_out, int out_size, void* d_ws, size_t ws_size,
                              hipStream_t stream) {
    const float* hs  = (const float*)d_in[0];
    const float* rot = (const float*)d_in[1];
    const float* Wq  = (const float*)d_in[2];
    const float* bq  = (const float*)d_in[3];
    const float* Wk  = (const float*)d_in[4];
    const float* bk  = (const float*)d_in[5];
    const float* Wv  = (const float*)d_in[6];
    const float* bv  = (const float*)d_in[7];
    const float* nqw = (const float*)d_in[8];
    const float* nkw = (const float*)d_in[9];
    const float* hks = (const float*)d_in[10];
    const float* Wo  = (const float*)d_in[11];
    const float* bo  = (const float*)d_in[12];
    const int*   ocl = (const int*)d_in[13];

    // ws (64 MiB): qraw | kraw | vtr | aout, 16 MiB each
    u16* qraw = (u16*)d_ws;
    u16* kraw = qraw + 8388608;
    u16* vtr  = kraw + 8388608;
    u16* aout = vtr + 8388608;
    float* out = (float*)d_out;
    u16* hs16 = (u16*)d_out;   // scratch in d_out, dead before gemm_out writes

    cvt_hs<<<dim3(4096), 256, 0, stream>>>(hs, hs16);
    gemm_qkv<<<dim3(16, 32, 3), 256, 0, stream>>>(
        hs16, Wq, Wk, Wv, bq, bk, bv, qraw, kraw, vtr);
    norm_rope<<<dim3(4096), 256, 0, stream>>>(qraw, kraw, rot, nqw, nkw, hks, ocl);
    flash_attn3<<<dim3(16, 32), 512, 0, stream>>>(qraw, kraw, vtr, aout);
    gemm_out<<<dim3(16, 32), 256, 0, stream>>>(aout, Wo, bo, out);
}

// Round 6
// 536.575 us; speedup vs baseline: 1.7305x; 1.1383x over previous
//
#include <hip/hip_runtime.h>
#include <math.h>

typedef unsigned short u16;
typedef unsigned short u16x8 __attribute__((ext_vector_type(8)));
typedef _Float16 f16x8 __attribute__((ext_vector_type(8)));
typedef float f32x4 __attribute__((ext_vector_type(4)));

#define LOG2E 1.4426950408889634f

static __device__ __forceinline__ u16 f2h(float f) { return __builtin_bit_cast(u16, (_Float16)f); }
static __device__ __forceinline__ float h2f(u16 u) { return (float)__builtin_bit_cast(_Float16, u); }

// async global->LDS, 16B per lane; LDS dest = wave-uniform base + lane*16
static __device__ __forceinline__ void g2l16(const u16* g, u16* l) {
    __builtin_amdgcn_global_load_lds(
        (const __attribute__((address_space(1))) void*)g,
        (__attribute__((address_space(3))) void*)l, 16, 0, 0);
}

static __device__ __forceinline__ u16x8 ld8f(const float* p) {
    f32x4 a = *(const f32x4*)p;
    f32x4 b = *(const f32x4*)(p + 4);
    u16x8 r;
    r[0] = f2h(a[0]); r[1] = f2h(a[1]); r[2] = f2h(a[2]); r[3] = f2h(a[3]);
    r[4] = f2h(b[0]); r[5] = f2h(b[1]); r[6] = f2h(b[2]); r[7] = f2h(b[3]);
    return r;
}

// ---------------------------------------------------------------------------
// fused fp32->f16 convert: hs (4096 blk) + Wq + Wk + Wv (2048 blk each)
// ---------------------------------------------------------------------------
__global__ __launch_bounds__(256) void cvt4(
    const float* __restrict__ hs, const float* __restrict__ Wq,
    const float* __restrict__ Wk, const float* __restrict__ Wv,
    u16* __restrict__ hs16, u16* __restrict__ wq16,
    u16* __restrict__ wk16, u16* __restrict__ wv16)
{
    int blk = blockIdx.x;
    const float* s; u16* d;
    if (blk < 4096)      { s = hs; d = hs16; }
    else if (blk < 6144) { s = Wq; d = wq16; blk -= 4096; }
    else if (blk < 8192) { s = Wk; d = wk16; blk -= 6144; }
    else                 { s = Wv; d = wv16; blk -= 8192; }
    const size_t e = ((size_t)blk * 256 + threadIdx.x) * 8;
    *(u16x8*)(d + e) = ld8f(s + e);
}

__global__ __launch_bounds__(256) void cvt1(const float* __restrict__ s, u16* __restrict__ d) {
    const size_t e = ((size_t)blockIdx.x * 256 + threadIdx.x) * 8;
    *(u16x8*)(d + e) = ld8f(s + e);
}

// ---------------------------------------------------------------------------
// QKV GEMM, full-async (m97 structure): A and W16 both via global_load_lds,
// unpadded XOR-swizzled LDS, zero staging VALU. 128x128 tile, BK=32.
// z=0->Q, 1->K ([b*s][h*d]); z=2->V transposed [b,h,d,s].
// ---------------------------------------------------------------------------
__global__ __launch_bounds__(256) void gemm_qkv(
    const u16* __restrict__ A,
    const u16* __restrict__ W0, const u16* __restrict__ W1, const u16* __restrict__ W2,
    const float* __restrict__ B0, const float* __restrict__ B1, const float* __restrict__ B2,
    u16* __restrict__ Cq, u16* __restrict__ Ck, u16* __restrict__ Cvt)
{
    constexpr int K = 2048, N = 2048;
    const int z = blockIdx.z;
    const u16* W      = (z == 0) ? W0 : ((z == 1) ? W1 : W2);
    const float* bias = (z == 0) ? B0 : ((z == 1) ? B1 : B2);
    const int m0 = blockIdx.y * 128, n0 = blockIdx.x * 128;

    __shared__ __attribute__((aligned(16))) u16 As[128 * 32];
    __shared__ __attribute__((aligned(16))) u16 Bs[128 * 32];

    const int tid = threadIdx.x, l = tid & 63, w = tid >> 6;
    const int quad = l >> 4, lan = l & 15;

    // staging: wave w covers rows [w*32, w*32+32), source col-group XOR'd by row>>2
    const int sr = l >> 2, gcol = l & 3;
    const int gs0 = (gcol ^ ((w * 8 + (sr >> 2)) & 3)) * 8;
    const int gs1 = (gcol ^ ((w * 8 + 4 + (sr >> 2)) & 3)) * 8;
    const u16* pA0 = A + (size_t)(m0 + w * 32 + sr) * K + gs0;
    const u16* pA1 = A + (size_t)(m0 + w * 32 + 16 + sr) * K + gs1;
    const u16* pB0 = W + (size_t)(n0 + w * 32 + sr) * K + gs0;
    const u16* pB1 = W + (size_t)(n0 + w * 32 + 16 + sr) * K + gs1;
    u16* lA0 = &As[(w * 32) * 32];
    u16* lA1 = &As[(w * 32 + 16) * 32];
    u16* lB0 = &Bs[(w * 32) * 32];
    u16* lB1 = &Bs[(w * 32 + 16) * 32];

    const int wm = (w >> 1) * 64, wn = (w & 1) * 64;
    const int swq = (quad ^ ((lan >> 2) & 3)) * 8;   // frag col-group, same XOR key

    f32x4 acc[4][4] = {};

    for (int kt = 0; kt < K; kt += 32) {
        __syncthreads();                 // prev tile's readers done
        g2l16(pA0 + kt, lA0);
        g2l16(pA1 + kt, lA1);
        g2l16(pB0 + kt, lB0);
        g2l16(pB1 + kt, lB1);
        __syncthreads();                 // drain DMA

        f16x8 af[4], bf[4];
#pragma unroll
        for (int i = 0; i < 4; i++)
            af[i] = __builtin_bit_cast(f16x8, *(const u16x8*)(&As[(wm + i * 16 + lan) * 32 + swq]));
#pragma unroll
        for (int j = 0; j < 4; j++)
            bf[j] = __builtin_bit_cast(f16x8, *(const u16x8*)(&Bs[(wn + j * 16 + lan) * 32 + swq]));
#pragma unroll
        for (int i = 0; i < 4; i++)
#pragma unroll
            for (int j = 0; j < 4; j++)
                acc[i][j] = __builtin_amdgcn_mfma_f32_16x16x32_f16(af[i], bf[j], acc[i][j], 0, 0, 0);
    }

    if (z < 2) {
        u16* C = (z == 0) ? Cq : Ck;
#pragma unroll
        for (int j = 0; j < 4; j++) {
            const int col = n0 + wn + j * 16 + lan;
            const float bj = bias[col];
#pragma unroll
            for (int i = 0; i < 4; i++)
#pragma unroll
                for (int r = 0; r < 4; r++) {
                    const int row = m0 + wm + i * 16 + quad * 4 + r;
                    C[(size_t)row * N + col] = f2h(acc[i][j][r] + bj);
                }
        }
    } else {
        // V transposed: row=(b,s), col=(h,d) -> Cvt[((b*16+h)*128+d)*2048 + s]
#pragma unroll
        for (int j = 0; j < 4; j++) {
            const int col = n0 + wn + j * 16 + lan;
            const int hh = col >> 7, dd = col & 127;
            const float bj = bias[col];
            u16* Cr = Cvt + ((size_t)hh * 128 + dd) * 2048;
#pragma unroll
            for (int i = 0; i < 4; i++)
#pragma unroll
                for (int r = 0; r < 4; r++) {
                    const int row = m0 + wm + i * 16 + quad * 4 + r;
                    const int bb = row >> 11, ss = row & 2047;
                    Cr[(size_t)bb * 4194304 + ss] = f2h(acc[i][j][r] + bj);
                }
        }
    }
}

// ---------------------------------------------------------------------------
// RMSNorm + RoPE + history key scale; in-place f16 q/k; q *= 1/sqrt(128).
// ---------------------------------------------------------------------------
__global__ __launch_bounds__(256) void norm_rope(
    u16* __restrict__ q, u16* __restrict__ k,
    const float* __restrict__ rot,
    const float* __restrict__ nqw, const float* __restrict__ nkw,
    const float* __restrict__ hks, const int* __restrict__ oclp)
{
    const int row = blockIdx.x;
    const int s = row & 2047;
    const int t = threadIdx.x;
    const size_t base = (size_t)row * 2048 + t * 8;

    u16x8 q8 = *(const u16x8*)(q + base);
    u16x8 k8 = *(const u16x8*)(k + base);

    float qf[8], kf[8];
    float sq = 0.f, sk = 0.f;
#pragma unroll
    for (int i = 0; i < 8; i++) {
        qf[i] = h2f(q8[i]); sq += qf[i] * qf[i];
        kf[i] = h2f(k8[i]); sk += kf[i] * kf[i];
    }
#pragma unroll
    for (int off = 32; off > 0; off >>= 1) {
        sq += __shfl_down(sq, off);
        sk += __shfl_down(sk, off);
    }
    __shared__ float rq[4], rk[4];
    const int wv = t >> 6;
    if ((t & 63) == 0) { rq[wv] = sq; rk[wv] = sk; }
    __syncthreads();
    const float tq = rq[0] + rq[1] + rq[2] + rq[3];
    const float tk = rk[0] + rk[1] + rk[2] + rk[3];
    const float scq = rsqrtf(tq * (1.0f / 2048.0f) + 1e-5f);
    const float sck = rsqrtf(tk * (1.0f / 2048.0f) + 1e-5f);
#pragma unroll
    for (int i = 0; i < 8; i++) {
        qf[i] *= scq * nqw[t * 8 + i];
        kf[i] *= sck * nkw[t * 8 + i];
    }
    const int e0 = t * 8;
    const int dh0 = e0 & 127;
    const int h = e0 >> 7;
    float qo[8], ko[8];
#pragma unroll
    for (int p = 0; p < 4; p++) {
        const int dh = dh0 + 2 * p;
        const float c  = rot[s * 256 + dh];
        const float sn = rot[s * 256 + 128 + dh + 1];
        qo[2 * p]     = qf[2 * p] * c  - qf[2 * p + 1] * sn;
        qo[2 * p + 1] = qf[2 * p] * sn + qf[2 * p + 1] * c;
        ko[2 * p]     = kf[2 * p] * c  - kf[2 * p + 1] * sn;
        ko[2 * p + 1] = kf[2 * p] * sn + kf[2 * p + 1] * c;
    }
    const float ATT = 0.08838834764831845f;
#pragma unroll
    for (int i = 0; i < 8; i++) qo[i] *= ATT;

    const int hist = 2048 - oclp[0];
    if (s < hist) {
        const float hv = hks[h];
        const float scl = 1.0f + 9.0f / (1.0f + expf(-hv));
#pragma unroll
        for (int i = 0; i < 8; i++) ko[i] *= scl;
    }

    u16x8 qo8, ko8;
#pragma unroll
    for (int i = 0; i < 8; i++) { qo8[i] = f2h(qo[i]); ko8[i] = f2h(ko[i]); }
    *(u16x8*)(q + base) = qo8;
    *(u16x8*)(k + base) = ko8;
}

// ---------------------------------------------------------------------------
// Flash attention v4: K and pre-transposed V staged via global_load_lds with
// source-side XOR swizzle into unpadded double-buffered LDS; ONE barrier per
// K-tile (DMA for kt+1 issued before compute(kt)). 256 threads = 4 waves x
// 16 q-rows (64 q-rows/block), grid 32x32. LDS = 32+32+9 = 73 KB -> 2 blk/CU.
// ---------------------------------------------------------------------------
__global__ __launch_bounds__(256) void flash_attn4(
    const u16* __restrict__ Q, const u16* __restrict__ Kr, const u16* __restrict__ Vt,
    u16* __restrict__ O)
{
    const int qt = blockIdx.x;        // 0..31 (64 q-rows each)
    const int bh = blockIdx.y;        // 0..31
    const int b = bh >> 4, h = bh & 15;
    const int tid = threadIdx.x, l = tid & 63, w = tid >> 6;
    const int quad = l >> 4, lan = l & 15;

    __shared__ __attribute__((aligned(16))) u16 Kb[2][64 * 128];
    __shared__ __attribute__((aligned(16))) u16 VTb[2][128 * 64];
    __shared__ __attribute__((aligned(16))) u16 Pb[4][16 * 72];

    // Q A-frags (q pre-scaled by 1/sqrt(128))
    f16x8 qf[4];
    {
        const u16* qp = Q + ((size_t)(b * 2048 + qt * 64 + w * 16 + lan)) * 2048 + h * 128 + quad * 8;
#pragma unroll
        for (int ks = 0; ks < 4; ks++)
            qf[ks] = __builtin_bit_cast(f16x8, *(const u16x8*)(qp + ks * 32));
    }

    // K staging: 4 issues; issue i: row = w*4 + 16i + (l>>4), chunk l&15,
    // source chunk XOR'd by row&15. LDS base = (w*64 + 256i)*8 elems.
    const int krow_b = w * 4 + (l >> 4);           // +16i per issue
    const int kchk   = l & 15;
    const u16* kbase = Kr + ((size_t)(b * 2048)) * 2048 + h * 128;
    // VT staging: 4 issues; row = w*8 + 32i + (l>>3), chunk l&7, XOR by l>>3
    const int vrow_b = w * 8 + (l >> 3);           // +32i per issue
    const int vg     = ((l & 7) ^ (l >> 3)) * 8;
    const u16* vbase = Vt + ((size_t)((b * 16 + h) * 128)) * 2048;

    float mr[4], lrp[4];
    f32x4 o[8] = {};
#pragma unroll
    for (int r = 0; r < 4; r++) { mr[r] = -3.0e38f; lrp[r] = 0.f; }

    // issue DMA for tile 0 into buf 0
#pragma unroll
    for (int i = 0; i < 4; i++) {
        const int kr = krow_b + 16 * i;
        g2l16(kbase + (size_t)kr * 2048 + ((kchk ^ (kr & 15)) * 8), &Kb[0][(w * 64 + 256 * i) * 8]);
    }
#pragma unroll
    for (int i = 0; i < 4; i++) {
        const int vr = vrow_b + 32 * i;
        g2l16(vbase + (size_t)vr * 2048 + vg, &VTb[0][(w * 64 + 256 * i) * 8]);
    }
    __syncthreads();   // drain tile-0 DMA

    for (int kt = 0; kt < 32; kt++) {
        const int buf = kt & 1;
        // prefetch tile kt+1 into other buffer (completes during compute)
        if (kt < 31) {
            const int kn = (kt + 1) * 64;
#pragma unroll
            for (int i = 0; i < 4; i++) {
                const int kr = krow_b + 16 * i;
                g2l16(kbase + (size_t)(kn + kr) * 2048 + ((kchk ^ (kr & 15)) * 8),
                      &Kb[buf ^ 1][(w * 64 + 256 * i) * 8]);
            }
#pragma unroll
            for (int i = 0; i < 4; i++) {
                const int vr = vrow_b + 32 * i;
                g2l16(vbase + (size_t)vr * 2048 + kn + vg,
                      &VTb[buf ^ 1][(w * 64 + 256 * i) * 8]);
            }
        }

        // S = Q K^T  (16 x 64 per wave); Kb chunk' = (ks*4+quad) ^ lan
        f32x4 sfr[4] = {};
#pragma unroll
        for (int ks = 0; ks < 4; ks++)
#pragma unroll
            for (int nt = 0; nt < 4; nt++) {
                f16x8 kb = __builtin_bit_cast(f16x8, *(const u16x8*)(
                    &Kb[buf][(nt * 16 + lan) * 128 + (((ks * 4 + quad) ^ lan) * 8)]));
                sfr[nt] = __builtin_amdgcn_mfma_f32_16x16x32_f16(qf[ks], kb, sfr[nt], 0, 0, 0);
            }

        // online softmax (quad max; deferred sum)
        float tm[4];
#pragma unroll
        for (int r = 0; r < 4; r++)
            tm[r] = fmaxf(fmaxf(sfr[0][r], sfr[1][r]), fmaxf(sfr[2][r], sfr[3][r]));
#pragma unroll
        for (int mask = 1; mask <= 8; mask <<= 1)
#pragma unroll
            for (int r = 0; r < 4; r++) tm[r] = fmaxf(tm[r], __shfl_xor(tm[r], mask));

        float al[4];
#pragma unroll
        for (int r = 0; r < 4; r++) {
            const float mn = fmaxf(mr[r], tm[r]);
            al[r] = exp2f((mr[r] - mn) * LOG2E);
            mr[r] = mn;
        }
        float ps[4] = {0.f, 0.f, 0.f, 0.f};
#pragma unroll
        for (int nt = 0; nt < 4; nt++)
#pragma unroll
            for (int r = 0; r < 4; r++) {
                const float p = exp2f((sfr[nt][r] - mr[r]) * LOG2E);
                ps[r] += p;
                Pb[w][(quad * 4 + r) * 72 + nt * 16 + lan] = f2h(p);
            }
#pragma unroll
        for (int r = 0; r < 4; r++) lrp[r] = lrp[r] * al[r] + ps[r];
#pragma unroll
        for (int nd = 0; nd < 8; nd++)
#pragma unroll
            for (int r = 0; r < 4; r++) o[nd][r] *= al[r];

        __asm__ volatile("s_waitcnt lgkmcnt(0)" ::: "memory");  // own-wave P visible

        // O += P @ V ; VTb chunk' = (ks2*4+quad) ^ (lan&7)
#pragma unroll
        for (int ks2 = 0; ks2 < 2; ks2++) {
            f16x8 pf = __builtin_bit_cast(f16x8,
                *(const u16x8*)(&Pb[w][lan * 72 + ks2 * 32 + quad * 8]));
#pragma unroll
            for (int nd = 0; nd < 8; nd++) {
                f16x8 vtf = __builtin_bit_cast(f16x8, *(const u16x8*)(
                    &VTb[buf][(nd * 16 + lan) * 64 + (((ks2 * 4 + quad) ^ (lan & 7)) * 8)]));
                o[nd] = __builtin_amdgcn_mfma_f32_16x16x32_f16(pf, vtf, o[nd], 0, 0, 0);
            }
        }

        __syncthreads();   // drains kt+1 DMA (had full compute to land) + syncs
    }

    // finalize deferred sums across the quad's 16 lanes
#pragma unroll
    for (int mask = 1; mask <= 8; mask <<= 1)
#pragma unroll
        for (int r = 0; r < 4; r++) lrp[r] += __shfl_xor(lrp[r], mask);

#pragma unroll
    for (int nd = 0; nd < 8; nd++)
#pragma unroll
        for (int r = 0; r < 4; r++) {
            const int srow = qt * 64 + w * 16 + quad * 4 + r;
            O[((size_t)(b * 2048 + srow)) * 2048 + h * 128 + nd * 16 + lan] = f2h(o[nd][r] / lrp[r]);
        }
}

// ---------------------------------------------------------------------------
// Output projection, full-async: A = aout f16, B = Wo16 f16, C fp32.
// ---------------------------------------------------------------------------
__global__ __launch_bounds__(256) void gemm_out(
    const u16* __restrict__ A, const u16* __restrict__ W,
    const float* __restrict__ bias, float* __restrict__ C)
{
    constexpr int K = 2048, N = 2048;
    const int m0 = blockIdx.y * 128, n0 = blockIdx.x * 128;

    __shared__ __attribute__((aligned(16))) u16 As[128 * 32];
    __shared__ __attribute__((aligned(16))) u16 Bs[128 * 32];

    const int tid = threadIdx.x, l = tid & 63, w = tid >> 6;
    const int quad = l >> 4, lan = l & 15;

    const int sr = l >> 2, gcol = l & 3;
    const int gs0 = (gcol ^ ((w * 8 + (sr >> 2)) & 3)) * 8;
    const int gs1 = (gcol ^ ((w * 8 + 4 + (sr >> 2)) & 3)) * 8;
    const u16* pA0 = A + (size_t)(m0 + w * 32 + sr) * K + gs0;
    const u16* pA1 = A + (size_t)(m0 + w * 32 + 16 + sr) * K + gs1;
    const u16* pB0 = W + (size_t)(n0 + w * 32 + sr) * K + gs0;
    const u16* pB1 = W + (size_t)(n0 + w * 32 + 16 + sr) * K + gs1;
    u16* lA0 = &As[(w * 32) * 32];
    u16* lA1 = &As[(w * 32 + 16) * 32];
    u16* lB0 = &Bs[(w * 32) * 32];
    u16* lB1 = &Bs[(w * 32 + 16) * 32];

    const int wm = (w >> 1) * 64, wn = (w & 1) * 64;
    const int swq = (quad ^ ((lan >> 2) & 3)) * 8;

    f32x4 acc[4][4] = {};

    for (int kt = 0; kt < K; kt += 32) {
        __syncthreads();
        g2l16(pA0 + kt, lA0);
        g2l16(pA1 + kt, lA1);
        g2l16(pB0 + kt, lB0);
        g2l16(pB1 + kt, lB1);
        __syncthreads();

        f16x8 af[4], bf[4];
#pragma unroll
        for (int i = 0; i < 4; i++)
            af[i] = __builtin_bit_cast(f16x8, *(const u16x8*)(&As[(wm + i * 16 + lan) * 32 + swq]));
#pragma unroll
        for (int j = 0; j < 4; j++)
            bf[j] = __builtin_bit_cast(f16x8, *(const u16x8*)(&Bs[(wn + j * 16 + lan) * 32 + swq]));
#pragma unroll
        for (int i = 0; i < 4; i++)
#pragma unroll
            for (int j = 0; j < 4; j++)
                acc[i][j] = __builtin_amdgcn_mfma_f32_16x16x32_f16(af[i], bf[j], acc[i][j], 0, 0, 0);
    }

#pragma unroll
    for (int j = 0; j < 4; j++) {
        const int col = n0 + wn + j * 16 + lan;
        const float bj = bias[col];
#pragma unroll
        for (int i = 0; i < 4; i++)
#pragma unroll
            for (int r = 0; r < 4; r++) {
                const int row = m0 + wm + i * 16 + quad * 4 + r;
                C[(size_t)row * N + col] = acc[i][j][r] + bj;
            }
    }
}

// ---------------------------------------------------------------------------
extern "C" void kernel_launch(void* const* d_in, const int* in_sizes, int n_in,
                              void* d_out, int out_size, void* d_ws, size_t ws_size,
                              hipStream_t stream) {
    const float* hs  = (const float*)d_in[0];
    const float* rot = (const float*)d_in[1];
    const float* Wq  = (const float*)d_in[2];
    const float* bq  = (const float*)d_in[3];
    const float* Wk  = (const float*)d_in[4];
    const float* bk  = (const float*)d_in[5];
    const float* Wv  = (const float*)d_in[6];
    const float* bv  = (const float*)d_in[7];
    const float* nqw = (const float*)d_in[8];
    const float* nkw = (const float*)d_in[9];
    const float* hks = (const float*)d_in[10];
    const float* Wo  = (const float*)d_in[11];
    const float* bo  = (const float*)d_in[12];
    const int*   ocl = (const int*)d_in[13];

    // ws (64 MiB): [0:16) qraw | [16:32) kraw | [32:48) vtr | [48:64) aout
    // aout region holds Wq16/Wk16 until flash overwrites it (they're dead then).
    u16* qraw = (u16*)d_ws;
    u16* kraw = qraw + 8388608;
    u16* vtr  = kraw + 8388608;
    u16* aout = vtr + 8388608;
    u16* wq16 = aout;                  // [48:56 MiB)
    u16* wk16 = aout + 4194304;        // [56:64 MiB)
    u16* wo16 = qraw;                  // reuses qraw AFTER flash
    float* out = (float*)d_out;
    u16* hs16 = (u16*)d_out;           // d_out [0:16 MiB)
    u16* wv16 = hs16 + 8388608;        // d_out [16:24 MiB)

    // 0) convert hs + Wq/Wk/Wv to f16
    cvt4<<<dim3(10240), 256, 0, stream>>>(hs, Wq, Wk, Wv, hs16, wq16, wk16, wv16);
    // 1) QKV projection (full async); z=2 writes V transposed [b,h,d,s]
    gemm_qkv<<<dim3(16, 32, 3), 256, 0, stream>>>(
        hs16, wq16, wk16, wv16, bq, bk, bv, qraw, kraw, vtr);
    // 2) rmsnorm + rope + history scale
    norm_rope<<<dim3(4096), 256, 0, stream>>>(qraw, kraw, rot, nqw, nkw, hks, ocl);
    // 3) flash attention (async-staged, 1 barrier/tile) -> aout
    flash_attn4<<<dim3(32, 32), 256, 0, stream>>>(qraw, kraw, vtr, aout);
    // 4) Wo -> f16 into dead qraw region, then output projection -> d_out
    cvt1<<<dim3(2048), 256, 0, stream>>>(Wo, wo16);
    gemm_out<<<dim3(16, 32), 256, 0, stream>>>(aout, wo16, bo, out);
}